// Round 4
// baseline (85.503 us; speedup 1.0000x reference)
//
#include <hip/hip_runtime.h>

#define TPB    256
#define NBLK   2048                // 8 blocks/CU -> 32 waves/CU (full occupancy)
#define WPB    (TPB / 64)
#define NWAVES (NBLK * WPB)        // 8192 waves; covers 2*8192*64 = 1,048,576 rows/pass

// pitch-class bitmask of a 4-note row. Values are integer-valued floats in
// [0,128); x%12 == x - 12*((x*683)>>13) exactly for 0<=x<=127.
__device__ __forceinline__ int pcmask(const float4 v) {
    int a = (int)v.x, b = (int)v.y, c = (int)v.z, d = (int)v.w;
    a -= 12 * ((a * 683) >> 13);
    b -= 12 * ((b * 683) >> 13);
    c -= 12 * ((c * 683) >> 13);
    d -= 12 * ((d * 683) >> 13);
    return (1 << a) | (1 << b) | (1 << c) | (1 << d);
}

// jaccard distance vs a 3-element template mask
__device__ __forceinline__ float jacc(int pm, int tm) {
    float p     = (float)__popc(pm);
    float inter = (float)__popc(pm & tm);
    return 1.0f - inter / (p + 3.0f - inter + 1e-8f);
}

// per-row terms for one 64-row wave chunk; pv/tv already loaded by caller
__device__ __forceinline__ void chunk_terms(int i, int n_win, int lane, bool valid,
                                            float4 pv, float4 tv,
                                            const float4* __restrict__ preds,
                                            float& sim, float& prog) {
    int pm = 0, tm = 0;
    sim = 0.0f; prog = 0.0f;
    if (valid) {
        pm = pcmask(pv);
        tm = pcmask(tv);
        float p     = (float)__popc(pm);
        float q     = (float)__popc(tm);
        float inter = (float)__popc(pm & tm);
        const float eps = 1e-6f;
        float num = inter + eps * (p + q) + 12.0f * eps * eps;
        float den = (p + 12.0f * eps) * (q + 12.0f * eps);
        sim = fminf(fmaxf(num / den, 0.0f), 1.0f);
    }
    // neighbor pred-masks via cross-lane; all 64 lanes execute the shuffles
    int m1 = __shfl_down(pm, 1);
    int m2 = __shfl_down(pm, 2);
    int m3 = __shfl_down(pm, 3);
    if (i < n_win) {
        if (lane >= 63) m1 = pcmask(preds[i + 1]);   // shuffle crossed wave
        if (lane >= 62) m2 = pcmask(preds[i + 2]);   // boundary: tiny L1/L2-hit
        if (lane >= 61) m3 = pcmask(preds[i + 3]);   // loads for 3 lanes
        float maj  = (jacc(pm, 0x091) + jacc(m1, 0x221) +
                      jacc(m2, 0x884) + jacc(m3, 0x091)) * 0.25f;
        float mino = (jacc(pm, 0x089) + jacc(m1, 0x121) +
                      jacc(m2, 0x484) + jacc(m3, 0x089)) * 0.25f;
        prog = fminf(maj, mino);
    }
}

// Stage 1: each wave owns contiguous 64-row chunks, unrolled x2 with all main
// loads issued up front (MLP). One double2 partial per block, no atomics.
__global__ void __launch_bounds__(TPB)
chord_partial_kernel(const float4* __restrict__ preds,
                     const float4* __restrict__ targs,
                     int T, int n_win,
                     double2* __restrict__ partials) {
    const int lane  = threadIdx.x & 63;
    const int gwave = blockIdx.x * WPB + (threadIdx.x >> 6);

    double s = 0.0, pg = 0.0;

    for (int base = gwave * 64; base < T; base += 2 * NWAVES * 64) {
        const int i0 = base + lane;
        const int i1 = i0 + NWAVES * 64;
        const bool v0 = (i0 < T);
        const bool v1 = (i1 < T);

        // issue all four 16B loads before any compute
        float4 pv0, tv0, pv1, tv1;
        if (v0) { pv0 = preds[i0]; tv0 = targs[i0]; }
        if (v1) { pv1 = preds[i1]; tv1 = targs[i1]; }

        float s0, p0, s1, p1;
        chunk_terms(i0, n_win, lane, v0, pv0, tv0, preds, s0, p0);
        chunk_terms(i1, n_win, lane, v1, pv1, tv1, preds, s1, p1);
        s  += (double)(s0 + s1);
        pg += (double)(p0 + p1);
    }

    // block reduction: wave shuffle, then LDS across waves
    #pragma unroll
    for (int off = 32; off > 0; off >>= 1) {
        s  += __shfl_down(s,  off);
        pg += __shfl_down(pg, off);
    }
    __shared__ double ls[WPB], lp[WPB];
    int wid = threadIdx.x >> 6;
    if (lane == 0) { ls[wid] = s; lp[wid] = pg; }
    __syncthreads();
    if (threadIdx.x == 0) {
        double st = 0.0, pt = 0.0;
        #pragma unroll
        for (int w = 0; w < WPB; ++w) { st += ls[w]; pt += lp[w]; }
        partials[blockIdx.x] = make_double2(st, pt);
    }
}

// Stage 2: one block reduces the 2048 partials and writes the scalar.
__global__ void __launch_bounds__(TPB)
chord_final_kernel(const double2* __restrict__ partials,
                   float* __restrict__ out, int T, int n_win) {
    double s = 0.0, pg = 0.0;
    for (int t = threadIdx.x; t < NBLK; t += TPB) {
        double2 v = partials[t];
        s  += v.x;
        pg += v.y;
    }
    #pragma unroll
    for (int off = 32; off > 0; off >>= 1) {
        s  += __shfl_down(s,  off);
        pg += __shfl_down(pg, off);
    }
    __shared__ double ls[TPB / 64], lp[TPB / 64];
    int wid = threadIdx.x >> 6, lane = threadIdx.x & 63;
    if (lane == 0) { ls[wid] = s; lp[wid] = pg; }
    __syncthreads();
    if (threadIdx.x == 0) {
        double st = 0.0, pt = 0.0;
        #pragma unroll
        for (int w = 0; w < TPB / 64; ++w) { st += ls[w]; pt += lp[w]; }
        out[0] = (float)((1.0 - st / (double)T) + 0.5 * (pt / (double)n_win));
    }
}

extern "C" void kernel_launch(void* const* d_in, const int* in_sizes, int n_in,
                              void* d_out, int out_size, void* d_ws, size_t ws_size,
                              hipStream_t stream) {
    const float4* preds = (const float4*)d_in[0];
    const float4* targs = (const float4*)d_in[1];
    float* out = (float*)d_out;
    double2* partials = (double2*)d_ws;   // NBLK double2 slots, fully overwritten

    int T     = in_sizes[0] / 4;   // rows
    int n_win = T - 3;

    chord_partial_kernel<<<NBLK, TPB, 0, stream>>>(preds, targs, T, n_win, partials);
    chord_final_kernel<<<1, TPB, 0, stream>>>(partials, out, T, n_win);
}

// Round 5
// 79.392 us; speedup vs baseline: 1.0770x; 1.0770x over previous
//
#include <hip/hip_runtime.h>

#define TPB 256
#define WPB (TPB / 64)   // waves per block

// pitch-class bitmask of a 4-note row. Values are integer-valued floats in
// [0,128); x/12 == (x*683)>>13 exactly for 0<=x<=127.
__device__ __forceinline__ int pcmask(const float4 v) {
    int a = (int)v.x, b = (int)v.y, c = (int)v.z, d = (int)v.w;
    a -= 12 * ((a * 683) >> 13);
    b -= 12 * ((b * 683) >> 13);
    c -= 12 * ((c * 683) >> 13);
    d -= 12 * ((d * 683) >> 13);
    return (1 << a) | (1 << b) | (1 << c) | (1 << d);
}

// jaccard distance vs a 3-note template, via 16-entry LDS table [(p-1)*4 + inter]
__device__ __forceinline__ float jtabv(int m, int tmpl, const float* __restrict__ jt) {
    int p = __popc(m);
    int i = __popc(m & tmpl);
    return jt[((p - 1) << 2) + i];
}

// similarity via 80-entry LDS table [((p-1)*4 + (q-1))*5 + inter]
__device__ __forceinline__ float simval(int pm, int tm, const float* __restrict__ st) {
    int p = __popc(pm), q = __popc(tm), i = __popc(pm & tm);
    return st[(((p - 1) << 2) + (q - 1)) * 5 + i];
}

// Stage 1: wave owns 128 contiguous rows (lane -> base+lane and base+64+lane).
// Straight-line, no loop. One double2 partial per block, no atomics.
__global__ void __launch_bounds__(TPB)
chord_partial_kernel(const float4* __restrict__ preds,
                     const float4* __restrict__ targs,
                     int T, int n_win,
                     double2* __restrict__ partials) {
    __shared__ float jtab[16];
    __shared__ float stab[80];
    __shared__ double ls[WPB], lp[WPB];

    const int t = threadIdx.x;
    if (t < 16) {                       // jaccard table: exact values
        int p = (t >> 2) + 1, i = t & 3;
        jtab[t] = 1.0f - (float)i / ((float)(p + 3 - i) + 1e-8f);
    } else if (t < 96) {                // sim table: exact closed form
        int u  = t - 16;
        int i  = u % 5, pq = u / 5;
        int p  = (pq >> 2) + 1, q = (pq & 3) + 1;
        const float eps = 1e-6f;
        float num = (float)i + eps * (float)(p + q) + 12.0f * eps * eps;
        float den = ((float)p + 12.0f * eps) * ((float)q + 12.0f * eps);
        stab[u] = fminf(fmaxf(num / den, 0.0f), 1.0f);
    }
    __syncthreads();

    const int lane  = t & 63;
    const int wid   = t >> 6;
    const int base  = (blockIdx.x * WPB + wid) * 128;
    const int i0    = base + lane;
    const int i1    = i0 + 64;

    // clamped unconditional loads (invalid rows duplicate last row; masked later)
    const int ic0 = min(i0, T - 1);
    const int ic1 = min(i1, T - 1);
    float4 pv0 = preds[ic0], tv0 = targs[ic0];
    float4 pv1 = preds[ic1], tv1 = targs[ic1];

    int pm0 = pcmask(pv0), tm0 = pcmask(tv0);
    int pm1 = pcmask(pv1), tm1 = pcmask(tv1);

    // half-0 neighbor masks: in-wave shuffles; lanes 61-63 pull from half-1
    int a1 = __shfl_down(pm0, 1), a2 = __shfl_down(pm0, 2), a3 = __shfl_down(pm0, 3);
    int c1 = __shfl(pm1, (lane + 1) & 63);
    int c2 = __shfl(pm1, (lane + 2) & 63);
    int c3 = __shfl(pm1, (lane + 3) & 63);
    int m1 = (lane < 63) ? a1 : c1;
    int m2 = (lane < 62) ? a2 : c2;
    int m3 = (lane < 61) ? a3 : c3;

    // half-1 neighbor masks: in-wave shuffles; lanes 61-63 cross into next wave
    int b1 = __shfl_down(pm1, 1), b2 = __shfl_down(pm1, 2), b3 = __shfl_down(pm1, 3);
    if (i1 < n_win) {                   // i1+3 <= T-1 guaranteed here
        if (lane == 63) b1 = pcmask(preds[i1 + 1]);
        if (lane >= 62) b2 = pcmask(preds[i1 + 2]);
        if (lane >= 61) b3 = pcmask(preds[i1 + 3]);
    }

    float s_acc = 0.0f, p_acc = 0.0f;
    if (i0 < T) s_acc += simval(pm0, tm0, stab);
    if (i1 < T) s_acc += simval(pm1, tm1, stab);

    if (i0 < n_win) {
        float maj = jtabv(pm0, 0x091, jtab) + jtabv(m1, 0x221, jtab) +
                    jtabv(m2,  0x884, jtab) + jtabv(m3, 0x091, jtab);
        float mn  = jtabv(pm0, 0x089, jtab) + jtabv(m1, 0x121, jtab) +
                    jtabv(m2,  0x484, jtab) + jtabv(m3, 0x089, jtab);
        p_acc += fminf(maj, mn);        // 0.25 factor applied in finalize
    }
    if (i1 < n_win) {
        float maj = jtabv(pm1, 0x091, jtab) + jtabv(b1, 0x221, jtab) +
                    jtabv(b2,  0x884, jtab) + jtabv(b3, 0x091, jtab);
        float mn  = jtabv(pm1, 0x089, jtab) + jtabv(b1, 0x121, jtab) +
                    jtabv(b2,  0x484, jtab) + jtabv(b3, 0x089, jtab);
        p_acc += fminf(maj, mn);
    }

    // block reduction: wave shuffle (double), then LDS across waves
    double s = (double)s_acc, pg = (double)p_acc;
    #pragma unroll
    for (int off = 32; off > 0; off >>= 1) {
        s  += __shfl_down(s,  off);
        pg += __shfl_down(pg, off);
    }
    if (lane == 0) { ls[wid] = s; lp[wid] = pg; }
    __syncthreads();
    if (t == 0) {
        double st = 0.0, pt = 0.0;
        #pragma unroll
        for (int w = 0; w < WPB; ++w) { st += ls[w]; pt += lp[w]; }
        partials[blockIdx.x] = make_double2(st, pt);
    }
}

// Stage 2: one block reduces the partials and writes the scalar.
__global__ void __launch_bounds__(TPB)
chord_final_kernel(const double2* __restrict__ partials,
                   float* __restrict__ out, int T, int n_win, int nblk) {
    double s = 0.0, pg = 0.0;
    for (int t = threadIdx.x; t < nblk; t += TPB) {
        double2 v = partials[t];
        s  += v.x;
        pg += v.y;
    }
    #pragma unroll
    for (int off = 32; off > 0; off >>= 1) {
        s  += __shfl_down(s,  off);
        pg += __shfl_down(pg, off);
    }
    __shared__ double ls[TPB / 64], lp[TPB / 64];
    int wid = threadIdx.x >> 6, lane = threadIdx.x & 63;
    if (lane == 0) { ls[wid] = s; lp[wid] = pg; }
    __syncthreads();
    if (threadIdx.x == 0) {
        double st = 0.0, pt = 0.0;
        #pragma unroll
        for (int w = 0; w < TPB / 64; ++w) { st += ls[w]; pt += lp[w]; }
        out[0] = (float)((1.0 - st / (double)T) +
                         0.5 * (0.25 * pt / (double)n_win));
    }
}

extern "C" void kernel_launch(void* const* d_in, const int* in_sizes, int n_in,
                              void* d_out, int out_size, void* d_ws, size_t ws_size,
                              hipStream_t stream) {
    const float4* preds = (const float4*)d_in[0];
    const float4* targs = (const float4*)d_in[1];
    float* out = (float*)d_out;
    double2* partials = (double2*)d_ws;   // nblk double2 slots, fully overwritten

    int T      = in_sizes[0] / 4;          // rows
    int n_win  = T - 3;
    int nwaves = (T + 127) / 128;          // 128 rows per wave, single pass
    int nblk   = (nwaves + WPB - 1) / WPB;

    chord_partial_kernel<<<nblk, TPB, 0, stream>>>(preds, targs, T, n_win, partials);
    chord_final_kernel<<<1, TPB, 0, stream>>>(partials, out, T, n_win, nblk);
}

// Round 6
// 77.970 us; speedup vs baseline: 1.0966x; 1.0182x over previous
//
#include <hip/hip_runtime.h>

#define TPB 256
#define WPB (TPB / 64)   // waves per block

// pitch-class bitmask of a 4-note row. Values are integer-valued floats in
// [0,128); x/12 == (x*683)>>13 exactly for 0<=x<=127 (24-bit mul safe).
__device__ __forceinline__ int pcmask(const float4 v) {
    int a = (int)v.x, b = (int)v.y, c = (int)v.z, d = (int)v.w;
    a -= 12 * (__mul24(a, 683) >> 13);
    b -= 12 * (__mul24(b, 683) >> 13);
    c -= 12 * (__mul24(c, 683) >> 13);
    d -= 12 * (__mul24(d, 683) >> 13);
    return (1 << a) | (1 << b) | (1 << c) | (1 << d);
}

// jaccard distance vs a 3-note template, via 16-entry LDS table [(p-1)*4 + inter]
__device__ __forceinline__ float jtabv(int m, int tmpl, const float* __restrict__ jt) {
    int p = __popc(m);
    int i = __popc(m & tmpl);
    return jt[((p - 1) << 2) + i];
}

// similarity via 80-entry LDS table [((p-1)*4 + (q-1))*5 + inter]
__device__ __forceinline__ float simval(int pm, int tm, const float* __restrict__ st) {
    int p = __popc(pm), q = __popc(tm), i = __popc(pm & tm);
    return st[(((p - 1) << 2) + (q - 1)) * 5 + i];
}

// Stage 1: wave owns 128 contiguous rows (lane -> base+lane, base+64+lane).
// Boundary rows base+128..130 loaded EARLY by lanes 0-2 and broadcast.
// Straight-line, no loop. One float2 partial per block, no atomics.
__global__ void __launch_bounds__(TPB)
chord_partial_kernel(const float4* __restrict__ preds,
                     const float4* __restrict__ targs,
                     int T, int n_win,
                     float2* __restrict__ partials) {
    __shared__ float jtab[16];
    __shared__ float stab[80];
    __shared__ float ls[WPB], lp[WPB];

    const int t = threadIdx.x;
    if (t < 16) {                       // jaccard table: exact values
        int p = (t >> 2) + 1, i = t & 3;
        jtab[t] = 1.0f - (float)i / ((float)(p + 3 - i) + 1e-8f);
    } else if (t < 96) {                // sim table: exact closed form
        int u  = t - 16;
        int i  = u % 5, pq = u / 5;
        int p  = (pq >> 2) + 1, q = (pq & 3) + 1;
        const float eps = 1e-6f;
        float num = (float)i + eps * (float)(p + q) + 12.0f * eps * eps;
        float den = ((float)p + 12.0f * eps) * ((float)q + 12.0f * eps);
        stab[u] = fminf(fmaxf(num / den, 0.0f), 1.0f);
    }
    __syncthreads();

    const int lane = t & 63;
    const int wid  = t >> 6;
    const int base = (blockIdx.x * WPB + wid) * 128;
    const int i0   = base + lane;
    const int i1   = i0 + 64;

    // all loads issued up front, clamped (invalid rows masked later)
    const int ic0 = min(i0, T - 1);
    const int ic1 = min(i1, T - 1);
    float4 pv0 = preds[ic0], tv0 = targs[ic0];
    float4 pv1 = preds[ic1], tv1 = targs[ic1];
    float4 pvx = preds[min(base + 128 + lane, T - 1)];   // only lanes 0-2 used

    int pm0 = pcmask(pv0), tm0 = pcmask(tv0);
    int pm1 = pcmask(pv1), tm1 = pcmask(tv1);
    int ext = pcmask(pvx);

    // boundary masks for rows base+128,129,130
    int e1 = __shfl(ext, 0), e2 = __shfl(ext, 1), e3 = __shfl(ext, 2);

    // half-0 neighbors: shfl_down within pm0, lanes 61-63 pull from pm1 rotate
    int a1 = __shfl_down(pm0, 1), a2 = __shfl_down(pm0, 2), a3 = __shfl_down(pm0, 3);
    int c1 = __shfl(pm1, (lane + 1) & 63);
    int c2 = __shfl(pm1, (lane + 2) & 63);
    int c3 = __shfl(pm1, (lane + 3) & 63);
    int m1 = (lane < 63) ? a1 : c1;
    int m2 = (lane < 62) ? a2 : c2;
    int m3 = (lane < 61) ? a3 : c3;

    // half-1 neighbors: reuse the c rotates (valid for lanes < 64-k),
    // wrap lanes take the e broadcasts
    int b1 = (lane == 63) ? e1 : c1;
    int b2 = (lane == 62) ? e1 : ((lane == 63) ? e2 : c2);
    int b3 = (lane == 61) ? e1 : ((lane == 62) ? e2 : ((lane == 63) ? e3 : c3));

    float s_acc = 0.0f, p_acc = 0.0f;
    if (i0 < T) s_acc += simval(pm0, tm0, stab);
    if (i1 < T) s_acc += simval(pm1, tm1, stab);

    if (i0 < n_win) {
        float maj = jtabv(pm0, 0x091, jtab) + jtabv(m1, 0x221, jtab) +
                    jtabv(m2,  0x884, jtab) + jtabv(m3, 0x091, jtab);
        float mn  = jtabv(pm0, 0x089, jtab) + jtabv(m1, 0x121, jtab) +
                    jtabv(m2,  0x484, jtab) + jtabv(m3, 0x089, jtab);
        p_acc += fminf(maj, mn);        // 0.25 factor applied in finalize
    }
    if (i1 < n_win) {
        float maj = jtabv(pm1, 0x091, jtab) + jtabv(b1, 0x221, jtab) +
                    jtabv(b2,  0x884, jtab) + jtabv(b3, 0x091, jtab);
        float mn  = jtabv(pm1, 0x089, jtab) + jtabv(b1, 0x121, jtab) +
                    jtabv(b2,  0x484, jtab) + jtabv(b3, 0x089, jtab);
        p_acc += fminf(maj, mn);
    }

    // block reduction in float (block sums <= 2048; err ~1e-3 << 2.6e-2 thresh)
    #pragma unroll
    for (int off = 32; off > 0; off >>= 1) {
        s_acc += __shfl_down(s_acc, off);
        p_acc += __shfl_down(p_acc, off);
    }
    if (lane == 0) { ls[wid] = s_acc; lp[wid] = p_acc; }
    __syncthreads();
    if (t == 0) {
        float st = 0.0f, pt = 0.0f;
        #pragma unroll
        for (int w = 0; w < WPB; ++w) { st += ls[w]; pt += lp[w]; }
        partials[blockIdx.x] = make_float2(st, pt);
    }
}

// Stage 2: one block reduces the partials (double accum) and writes the scalar.
__global__ void __launch_bounds__(TPB)
chord_final_kernel(const float2* __restrict__ partials,
                   float* __restrict__ out, int T, int n_win, int nblk) {
    double s = 0.0, pg = 0.0;
    for (int t = threadIdx.x; t < nblk; t += TPB) {
        float2 v = partials[t];
        s  += (double)v.x;
        pg += (double)v.y;
    }
    #pragma unroll
    for (int off = 32; off > 0; off >>= 1) {
        s  += __shfl_down(s,  off);
        pg += __shfl_down(pg, off);
    }
    __shared__ double ls[TPB / 64], lp[TPB / 64];
    int wid = threadIdx.x >> 6, lane = threadIdx.x & 63;
    if (lane == 0) { ls[wid] = s; lp[wid] = pg; }
    __syncthreads();
    if (threadIdx.x == 0) {
        double st = 0.0, pt = 0.0;
        #pragma unroll
        for (int w = 0; w < TPB / 64; ++w) { st += ls[w]; pt += lp[w]; }
        out[0] = (float)((1.0 - st / (double)T) +
                         0.5 * (0.25 * pt / (double)n_win));
    }
}

extern "C" void kernel_launch(void* const* d_in, const int* in_sizes, int n_in,
                              void* d_out, int out_size, void* d_ws, size_t ws_size,
                              hipStream_t stream) {
    const float4* preds = (const float4*)d_in[0];
    const float4* targs = (const float4*)d_in[1];
    float* out = (float*)d_out;
    float2* partials = (float2*)d_ws;   // nblk float2 slots, fully overwritten

    int T      = in_sizes[0] / 4;          // rows
    int n_win  = T - 3;
    int nwaves = (T + 127) / 128;          // 128 rows per wave, single pass
    int nblk   = (nwaves + WPB - 1) / WPB;

    chord_partial_kernel<<<nblk, TPB, 0, stream>>>(preds, targs, T, n_win, partials);
    chord_final_kernel<<<1, TPB, 0, stream>>>(partials, out, T, n_win, nblk);
}